// Round 3
// baseline (4346.446 us; speedup 1.0000x reference)
//
#include <hip/hip_runtime.h>
#include <stdint.h>

// Bidirectional GRU, 6 layers, H=256, S=512, B=10, fp32 in/out, bf16 MFMA.
// 7 live scans (fwd 0..5 + bwd 5). One 512-thread WG per scan; gates staged
// by helper WGs (6 per stream), consumed via global_load_lds.
// THIS ROUND — replace SC1 gate transport with release/acquire + cached DMA:
//   Rounds 0/1: two different binaries, dur identical to 0.01% => limiter is
//   the untouched path: per-step 32KB SC1 (MALL-direct) DMA + forced SC1
//   small-op RTTs. Fix:
//   1) scan: per-slot __builtin_amdgcn_fence(ACQUIRE, "agent") (emits L2
//      buffer_inv on gfx94x+) then CACHED global_load_lds (aux=0). Ring
//      reuse is safe: the inv drops the stale clean lines each step.
//   2) tag probe for slot t+2 issued at F(t-1), register-carried (full-step
//      flight); h-store + tag publishes moved AFTER the fence so the fence's
//      vmcnt(0) only drains full-step-old ops. htag shifted to (t-3).
//   3) back to proven 115,200B LDS (3 gate slots) — round-2's 147KB config
//      never validated (container failure).
// Producers keep sc1 write-through stores + vm0 + tag (MALL-visible,
// fence-independent). Data-before-tag: h(t-3) stored F(t-2), drained by
// fence vm0 @F(t-1), htag(t-3) published F(t).

typedef short short8 __attribute__((ext_vector_type(8)));
typedef float floatx4 __attribute__((ext_vector_type(4)));
typedef unsigned long long u64;
typedef unsigned int u32;
typedef unsigned short u16;

#define SEQ 512

// ws: gring 7*32 slots x 32KB (rz bf16 [512][16] + nx f32 [256][16]) = 7.34MB
//     hh   scans 0..4 [t:512][b:16][ch:128] bf16 = 10.5MB
//     tags u32: gtag[7][32] @0 ; htag[5][512] @256 ; cparr[7] @2816
#define GSLOT_U64 4096
#define GRING_U64 (7 * 32 * GSLOT_U64)
#define HH_U16 (5 * 512 * 2048)
#define TAGS_OFF_B ((size_t)GRING_U64 * 8 + (size_t)HH_U16 * 2)

__device__ __forceinline__ u16 f2bf(float f){ union{float f;u32 i;}v; v.f=f; u32 u=v.i; u += 0x7fffu + ((u>>16)&1u); return (u16)(u>>16); }
__device__ __forceinline__ float bf2f(u16 h){ union{u32 i;float f;}v; v.i=((u32)h)<<16; return v.f; }
__device__ __forceinline__ short8 ld8f(const float* p){
    float4 a=*(const float4*)p, b=*(const float4*)(p+4);
    short8 r; r[0]=(short)f2bf(a.x); r[1]=(short)f2bf(a.y); r[2]=(short)f2bf(a.z); r[3]=(short)f2bf(a.w);
    r[4]=(short)f2bf(b.x); r[5]=(short)f2bf(b.y); r[6]=(short)f2bf(b.z); r[7]=(short)f2bf(b.w); return r;
}
__device__ __forceinline__ short8 pk2(u64 a, u64 b){ union{u64 q[2]; short8 s;}v; v.q[0]=a; v.q[1]=b; return v.s; }
__device__ __forceinline__ u64 pack4bf(floatx4 a){
    return (u64)f2bf(a[0]) | ((u64)f2bf(a[1])<<16) | ((u64)f2bf(a[2])<<32) | ((u64)f2bf(a[3])<<48);
}
__device__ __forceinline__ float sigmoidf_(float x){ return 1.0f/(1.0f+__expf(-x)); }
__device__ __forceinline__ float tanhf_(float x){ float e=__expf(2.0f*x); return 1.0f-2.0f/(e+1.0f); }

#define ALD(p)    __hip_atomic_load((p), __ATOMIC_RELAXED, __HIP_MEMORY_SCOPE_AGENT)
#define AST(p,v)  __hip_atomic_store((p),(v),__ATOMIC_RELAXED,__HIP_MEMORY_SCOPE_AGENT)
__device__ __forceinline__ void wait_vm0(){ asm volatile("s_waitcnt vmcnt(0)" ::: "memory"); }
__device__ __forceinline__ void lgkm_barrier(){ asm volatile("s_waitcnt lgkmcnt(0)\n\ts_barrier" ::: "memory"); }
__device__ __forceinline__ void acq_agent(){ __builtin_amdgcn_fence(__ATOMIC_ACQUIRE, "agent"); }

// 16B device-scope (MALL write-through) store
__device__ __forceinline__ void st16_sc1(void* p, floatx4 v){
    asm volatile("global_store_dwordx4 %0, %1, off sc1" :: "v"(p), "v"(v) : "memory");
}

// global->LDS DMA, 16B/lane, CACHED (aux=0). Freshness across ring reuse is
// guaranteed by the acquire fence (L2 inv) executed just before issue.
__device__ __forceinline__ void dma16c(const void* g, void* l) {
    __builtin_amdgcn_global_load_lds(
        reinterpret_cast<const __attribute__((address_space(1))) unsigned int*>(
            (uintptr_t)g),
        reinterpret_cast<__attribute__((address_space(3))) unsigned int*>(
            (uintptr_t)l), 16, 0, 0);
}

__global__ __launch_bounds__(512, 2)
void gru_pipeline(const float* __restrict__ x,
                  const float* __restrict__ wihl0,
                  const float* __restrict__ wihrest,
                  const float* __restrict__ whh,
                  float* __restrict__ out,
                  u64* __restrict__ gring,
                  u16* __restrict__ hhb,
                  u32* __restrict__ tags)
{
    __shared__ u64 smem_[14400];   // 115,200 B: gbuf 3x32768 + hbuf 16,896 (proven size)
    const int blk  = blockIdx.x;
    const int tid  = threadIdx.x;
    const int w    = tid >> 6;
    const int lane = tid & 63;
    const int n16  = lane & 15;
    const int quad = lane >> 4;
    u32* cparr = tags + 2816;

    if (blk < 7) {
        // ================= SCAN: one 512-thread WG per scan =================
        const int s = blk;
        const int layer = (s==6)?5:s, dir=(s==6)?1:0;
        const float* whhp = whh + ((size_t)(layer*2+dir))*768*256;

        // W_hh B-frags: wave owns units j in [32w,32w+32): tiles m=g*2+u
        short8 bh[6][8];
#pragma unroll
        for (int g=0; g<3; ++g)
#pragma unroll
        for (int u=0; u<2; ++u) {
            const int row = g*256 + 32*w + 16*u + n16;
#pragma unroll
            for (int q=0; q<8; ++q)
                bh[g*2+u][q] = ld8f(whhp + (size_t)row*256 + q*32 + quad*8);
        }

        char* gb   = (char*)smem_;            // gate slots: [3][32768 B]
        u16*  hbuf = (u16*)(gb + 98304);      // [2][16][264] bf16
        for (int i=tid; i<8448; i+=512) hbuf[i] = 0;   // h(-1)=0 (both slots)

        u32* gtp = tags + s*32;
        u32* htp = tags + 256 + s*512;

        // prologue: stage gates(0), gates(1); probe tag(2)
        u32 tgP;
        {
#pragma unroll
            for (int p=0; p<2; ++p) {
                int gd=0;
                while (ALD(gtp + p) != (u32)(p+1)){ if(++gd>3000000) break; __builtin_amdgcn_s_sleep(2); }
                acq_agent();
                const char* sg = (const char*)(gring + (size_t)(s*32 + p)*GSLOT_U64);
#pragma unroll
                for (int r=0; r<4; ++r) dma16c(sg + (r*512+tid)*16, gb + p*32768 + (r*512+tid)*16);
            }
            tgP = ALD(gtp + 2);
            wait_vm0(); lgkm_barrier();
        }

        for (int t=0; t<SEQ; ++t) {
            // B: publish out(t-1) (s=5,6 only; plain cached stores)
            const u16* hbP = hbuf + (t&1)*4224;
            if (t >= 1 && s >= 5) {
                const int off = (s==6)?256:0;
#pragma unroll
                for (int k=0;k<5;++k) {
                    const int idx = tid + 512*k, b = idx >> 8, j = idx & 255;
                    if (b < 10)
                        out[(size_t)(t-1)*5120 + (size_t)b*512 + off + j] = bf2f(hbP[b*264 + j]);
                }
            }
            // D: acc init (r,z x-parts from slot t%3) + 48 MFMAs over K=256
            const char* g0 = gb + (t%3)*32768;
            floatx4 acc[6];
#pragma unroll
            for (int g=0; g<2; ++g)
#pragma unroll
            for (int u=0; u<2; ++u) {
                const int col = g*256 + 32*w + 16*u + n16;
                const u64 gw = *(const u64*)(g0 + col*32 + quad*8);
#pragma unroll
                for (int r=0; r<4; ++r) acc[g*2+u][r] = bf2f((u16)(gw >> (16*r)));
            }
            acc[4] = (floatx4){0.f,0.f,0.f,0.f};
            acc[5] = (floatx4){0.f,0.f,0.f,0.f};
#pragma unroll
            for (int q=0; q<8; ++q) {
                short8 ah = *(const short8*)(hbP + n16*264 + q*32 + quad*8);
#pragma unroll
                for (int m=0; m<6; ++m)
                    acc[m] = __builtin_amdgcn_mfma_f32_16x16x32_bf16(ah, bh[m][q], acc[m], 0,0,0);
            }
            // E: nonlinearity, h(t) -> LDS slot (t+1)&1
            u16* hbN = hbuf + ((t+1)&1)*4224;
            const float* nxp = (const float*)(g0 + 16384);
#pragma unroll
            for (int u=0; u<2; ++u) {
                const int j = 32*w + 16*u + n16;
                const floatx4 nx4 = *(const floatx4*)(nxp + j*16 + quad*4);
#pragma unroll
                for (int r=0; r<4; ++r) {
                    const int b = quad*4 + r;
                    float rr = sigmoidf_(acc[u][r]);
                    float zz = sigmoidf_(acc[2+u][r]);
                    float nn = tanhf_(nx4[r] + rr*acc[4+u][r]);
                    float hp = bf2f(hbP[b*264 + j]);
                    float hn = (1.0f-zz)*nn + zz*hp;
                    hbN[b*264 + j] = f2bf(hn);
                }
            }
            // F: confirm tag(t+2) (probed at F(t-1), full-step flight),
            // acquire fence (vm drain of full-step-old ops + L2 inv), then
            // issue: cached dma(t+2) -> slot (t+2)%3, probe(t+3), and the
            // post-fence small publishes (drain deadline = next fence).
            if (t+2 < SEQ) {
                if (tgP != (u32)(t+3)) {       // transient only
                    int gd=0;
                    while (ALD(gtp + ((t+2)&31)) != (u32)(t+3)){ if(++gd>3000000) break; __builtin_amdgcn_s_sleep(1); }
                }
                acq_agent();
                const char* sg = (const char*)(gring + (size_t)(s*32 + ((t+2)&31))*GSLOT_U64);
                char* dg = gb + ((t+2)%3)*32768;
#pragma unroll
                for (int r=0; r<4; ++r) dma16c(sg + (r*512+tid)*16, dg + (r*512+tid)*16);
                if (t+3 < SEQ) tgP = ALD(gtp + ((t+3)&31));
            } else {
                wait_vm0();
            }
            if (tid==0) {
                if ((t&3)==0) AST(cparr + s, (u32)(t+1));   // coarse progress
                if (s<=4 && t>=3) AST(htp + (t-3), (u32)(t-2));
            }
            if (t >= 1 && s<=4 && tid<256) {   // h(t-1) sc1 write-through
                const int b = tid & 15, k = tid >> 4;
                char* hq = (char*)(hhb + (size_t)s*1048576 + (size_t)(t-1)*2048);
                st16_sc1(hq + b*256 + k*16, *(const floatx4*)(hbP + b*264 + 8*k));
            }
            lgkm_barrier();
        }
        // epilogue: h(511)/out(511) live in slot (512&1)=0
        const u16* hbL = hbuf;
        if (s<=4) {
            if (tid < 256) {
                const int b = tid & 15, k = tid >> 4;
                char* hq = (char*)(hhb + (size_t)s*1048576 + (size_t)(SEQ-1)*2048);
                st16_sc1(hq + b*256 + k*16, *(const floatx4*)(hbL + b*264 + 8*k));
            }
        } else {
            const int off = (s==6)?256:0;
#pragma unroll
            for (int k=0;k<5;++k) {
                const int idx = tid + 512*k, b = idx >> 8, j = idx & 255;
                if (b < 10)
                    out[(size_t)(SEQ-1)*5120 + (size_t)b*512 + off + j] = bf2f(hbL[b*264 + j]);
            }
        }
        wait_vm0(); lgkm_barrier();
        if (tid==0 && s<=4) { AST(htp + 509, 510u); AST(htp + 510, 511u); AST(htp + 511, 512u); }
        return;
    }

    // ================= HELPERS: gates_x producers (6 WGs/stream) =================
    const int sh = (blk - 7) / 6;
    const int t0 = (blk - 7) % 6;

    const int layer = (sh==6)?5:sh, dir=(sh==6)?1:0;
    const float* wihp; int stride;
    if (layer==0){ wihp = wihl0 + (size_t)dir*768*128; stride=128; }
    else         { wihp = wihrest + ((size_t)((layer-1)*2+dir))*768*512; stride=512; }

    // 8 waves x 6 tiles: gate col = (w*6+i)*16 + n16
    short8 bxf[6][4];
#pragma unroll
    for (int i=0; i<6; ++i) {
        const int col = (w*6+i)*16 + n16;
#pragma unroll
        for (int q=0; q<4; ++q)
            bxf[i][q] = ld8f(wihp + (size_t)col*stride + q*32 + quad*8);
    }
    char* tb = (char*)smem_;               // 32 KB slot image
    const int bmA = (n16>9)?9:n16;
    const int lsrc = (sh==6)? 4 : (sh-1);
    u32* gtp_sh = tags + sh*32;

    for (int t = t0; t < SEQ; t += 6) {
        if (t >= 32) {   // ring-32 flow control vs consumer scan (lead <= ~27)
            int gd=0;
            while ((int)ALD(cparr + sh) < t-24){ if(++gd>1000000) break; __builtin_amdgcn_s_sleep(8); }
        }
        short8 ax[4];
        if (sh == 0) {
            const float* xr = x + (size_t)t*1280 + (size_t)bmA*128;
#pragma unroll
            for (int q=0; q<4; ++q) ax[q] = ld8f(xr + q*32 + quad*8);
        } else {
            const int srct = (sh==6)? (SEQ-1-t) : t;
            int gd=0;
            while (ALD(tags + 256 + lsrc*512 + srct) != (u32)(srct+1)){ if(++gd>3000000) break; __builtin_amdgcn_s_sleep(4); }
            const u64* hq = (const u64*)(hhb + (size_t)lsrc*1048576 + (size_t)srct*2048);
#pragma unroll
            for (int q=0; q<4; ++q) {
                u64 a = ALD(hq + n16*32 + q*8 + quad*2);
                u64 b = ALD(hq + n16*32 + q*8 + quad*2 + 1);
                ax[q] = pk2(a, b);
            }
        }
        floatx4 acc[6];
#pragma unroll
        for (int i=0; i<6; ++i) acc[i] = (floatx4){0.f,0.f,0.f,0.f};
#pragma unroll
        for (int q=0; q<4; ++q)
#pragma unroll
            for (int i=0; i<6; ++i)
                acc[i] = __builtin_amdgcn_mfma_f32_16x16x32_bf16(ax[q], bxf[i][q], acc[i], 0,0,0);

        // slot image in LDS: rz bf16 [col<512][16], nx f32 [col-512][16]
#pragma unroll
        for (int i=0; i<6; ++i) {
            const int col = (w*6+i)*16 + n16;
            if (col < 512) *(u64*)(tb + col*32 + quad*8) = pack4bf(acc[i]);
            else           *(floatx4*)(tb + 16384 + (col-512)*64 + quad*16) = acc[i];
        }
        __syncthreads();
        // publish 32KB slot: 4x 16B sc1 write-through stores, drain, tag.
        char* gq = (char*)(gring + (size_t)(sh*32 + (t&31))*GSLOT_U64);
#pragma unroll
        for (int k=0;k<4;++k)
            st16_sc1(gq + tid*64 + k*16, *(const floatx4*)((const char*)tb + tid*64 + k*16));
        wait_vm0();
        __syncthreads();     // all waves' stores MALL-visible; tb reusable
        if (tid==0) AST(gtp_sh + (t&31), (u32)(t+1));
    }
}

extern "C" void kernel_launch(void* const* d_in, const int* in_sizes, int n_in,
                              void* d_out, int out_size, void* d_ws, size_t ws_size,
                              hipStream_t stream) {
    (void)in_sizes; (void)n_in; (void)out_size; (void)ws_size;
    const float* x       = (const float*)d_in[0];
    const float* wihl0   = (const float*)d_in[1];
    const float* wihrest = (const float*)d_in[2];
    const float* whh     = (const float*)d_in[3];
    float* out = (float*)d_out;
    u64* gring = (u64*)d_ws;
    u16* hhb   = (u16*)((char*)d_ws + (size_t)GRING_U64*8);
    u32* tags  = (u32*)((char*)d_ws + TAGS_OFF_B);

    // No memset: 0xAAAAAAAA poison never equals a valid tag (1..512);
    // flow-control reads cast to int (poison negative => "not yet").
    gru_pipeline<<<dim3(49), dim3(512), 0, stream>>>(x, wihl0, wihrest, whh, out,
                                                     gring, hhb, tags);
}

// Round 4
// 4110.504 us; speedup vs baseline: 1.0574x; 1.0574x over previous
//
#include <hip/hip_runtime.h>
#include <stdint.h>

// Bidirectional GRU, 6 layers, H=256, S=512, B=10, fp32 in/out, bf16 MFMA.
// 7 live scans (fwd 0..5 + bwd 5). One 512-thread WG per scan; gates staged
// by helper WGs (3 per stream), consumed via global_load_lds (SC1).
// THIS ROUND — DVFS probe/fix: rounds 0-3 proved transport is NOT the
// limiter (3 different transports within 8%; two binaries identical to
// 0.01%). Real per-step cycle count is ~2000 cy but measures 3.9us =>
// hypothesis: ~1% occupancy parks the engine clock at ~500MHz. Add 200
// burner WGs (dense reg-only FP32 FMA) on idle CUs to force the governor
// to high clock. Static 115,200B LDS means burners are 1 WG/CU and can
// never co-reside with scans/helpers (no issue-slot theft). Burners spin
// until scan 6 bumps a monotonic done-counter (poison-safe: exit on CHANGE
// from captured start value; correct across graph replays, no memset).
// Scan/helper logic = round-1 verified config, byte-for-byte.

typedef short short8 __attribute__((ext_vector_type(8)));
typedef float floatx4 __attribute__((ext_vector_type(4)));
typedef unsigned long long u64;
typedef unsigned int u32;
typedef unsigned short u16;

#define SEQ 512

// ws: gring 7*32 slots x 32KB (rz bf16 [512][16] + nx f32 [256][16]) = 7.34MB
//     hh   scans 0..4 [t:512][b:16][ch:128] bf16 = 10.5MB
//     tags u32: gtag[7][32] @0 ; htag[5][512] @256 ; cparr[7] @2816 ;
//               done @3072 (own line, far from polled tags)
#define GSLOT_U64 4096
#define GRING_U64 (7 * 32 * GSLOT_U64)
#define HH_U16 (5 * 512 * 2048)
#define TAGS_OFF_B ((size_t)GRING_U64 * 8 + (size_t)HH_U16 * 2)
#define DONE_OFF 3072

__device__ __forceinline__ u16 f2bf(float f){ union{float f;u32 i;}v; v.f=f; u32 u=v.i; u += 0x7fffu + ((u>>16)&1u); return (u16)(u>>16); }
__device__ __forceinline__ float bf2f(u16 h){ union{u32 i;float f;}v; v.i=((u32)h)<<16; return v.f; }
__device__ __forceinline__ short8 ld8f(const float* p){
    float4 a=*(const float4*)p, b=*(const float4*)(p+4);
    short8 r; r[0]=(short)f2bf(a.x); r[1]=(short)f2bf(a.y); r[2]=(short)f2bf(a.z); r[3]=(short)f2bf(a.w);
    r[4]=(short)f2bf(b.x); r[5]=(short)f2bf(b.y); r[6]=(short)f2bf(b.z); r[7]=(short)f2bf(b.w); return r;
}
__device__ __forceinline__ short8 pk2(u64 a, u64 b){ union{u64 q[2]; short8 s;}v; v.q[0]=a; v.q[1]=b; return v.s; }
__device__ __forceinline__ u64 pack4bf(floatx4 a){
    return (u64)f2bf(a[0]) | ((u64)f2bf(a[1])<<16) | ((u64)f2bf(a[2])<<32) | ((u64)f2bf(a[3])<<48);
}
__device__ __forceinline__ float sigmoidf_(float x){ return 1.0f/(1.0f+__expf(-x)); }
__device__ __forceinline__ float tanhf_(float x){ float e=__expf(2.0f*x); return 1.0f-2.0f/(e+1.0f); }

#define ALD(p)    __hip_atomic_load((p), __ATOMIC_RELAXED, __HIP_MEMORY_SCOPE_AGENT)
#define AST(p,v)  __hip_atomic_store((p),(v),__ATOMIC_RELAXED,__HIP_MEMORY_SCOPE_AGENT)
__device__ __forceinline__ void wait_vm0(){ asm volatile("s_waitcnt vmcnt(0)" ::: "memory"); }
__device__ __forceinline__ void wait_vm4(){ asm volatile("s_waitcnt vmcnt(4)" ::: "memory"); }
__device__ __forceinline__ void lgkm_barrier(){ asm volatile("s_waitcnt lgkmcnt(0)\n\ts_barrier" ::: "memory"); }

// 16B device-scope (MALL-visible) store: sc1 cache policy at dwordx4 width.
__device__ __forceinline__ void st16_sc1(void* p, floatx4 v){
    asm volatile("global_store_dwordx4 %0, %1, off sc1" :: "v"(p), "v"(v) : "memory");
}

// global->LDS DMA, 16B/lane, aux=16 (SC1: device-scope, bypass per-XCD L2)
__device__ __forceinline__ void dma16(const void* g, void* l) {
    __builtin_amdgcn_global_load_lds(
        reinterpret_cast<const __attribute__((address_space(1))) unsigned int*>(
            (uintptr_t)g),
        reinterpret_cast<__attribute__((address_space(3))) unsigned int*>(
            (uintptr_t)l), 16, 0, 16);
}

__global__ __launch_bounds__(512, 2)
void gru_pipeline(const float* __restrict__ x,
                  const float* __restrict__ wihl0,
                  const float* __restrict__ wihrest,
                  const float* __restrict__ whh,
                  float* __restrict__ out,
                  u64* __restrict__ gring,
                  u16* __restrict__ hhb,
                  u32* __restrict__ tags)
{
    __shared__ u64 smem_[14400];   // 115,200 B: reserved by ALL blocks => 1 block/CU everywhere
    const int blk  = blockIdx.x;
    const int tid  = threadIdx.x;
    const int w    = tid >> 6;
    const int lane = tid & 63;
    const int n16  = lane & 15;
    const int quad = lane >> 4;
    u32* cparr = tags + 2816;

    if (blk >= 28) {
        // ================= BURNERS: clock-floor keepers =================
        // Dense reg-only FMA; poll done-counter every ~8192 FMA (~3.5us @2.4GHz).
        // Exit on CHANGE from start value (poison-safe, replay-safe).
        u32* flag = tags + DONE_OFF;
        const u32 fv0 = ALD(flag);
        float r0 = 1.0f + tid*1e-3f, r1 = r0+0.1f, r2 = r0+0.2f, r3 = r0+0.3f;
        float r4 = r0+0.4f, r5 = r0+0.5f, r6 = r0+0.6f, r7 = r0+0.7f;
        const float c1 = 1.0000001f, c2 = 1e-7f;
        for (int chunk = 0; chunk < 30000; ++chunk) {      // failsafe cap
            for (int rep = 0; rep < 1024; ++rep) {
                r0 = __builtin_fmaf(r0, c1, c2); r1 = __builtin_fmaf(r1, c1, c2);
                r2 = __builtin_fmaf(r2, c1, c2); r3 = __builtin_fmaf(r3, c1, c2);
                r4 = __builtin_fmaf(r4, c1, c2); r5 = __builtin_fmaf(r5, c1, c2);
                r6 = __builtin_fmaf(r6, c1, c2); r7 = __builtin_fmaf(r7, c1, c2);
            }
            if (ALD(flag) != fv0) break;
        }
        // keep the math alive; never true in practice
        if (r0+r1+r2+r3+r4+r5+r6+r7 == 3.141592f)
            AST(tags + DONE_OFF + 1, 1u);
        return;
    }

    if (blk < 7) {
        // ================= SCAN: one 512-thread WG per scan =================
        const int s = blk;
        const int layer = (s==6)?5:s, dir=(s==6)?1:0;
        const float* whhp = whh + ((size_t)(layer*2+dir))*768*256;

        // W_hh B-frags: wave owns units j in [32w,32w+32): tiles m=g*2+u
        short8 bh[6][8];
#pragma unroll
        for (int g=0; g<3; ++g)
#pragma unroll
        for (int u=0; u<2; ++u) {
            const int row = g*256 + 32*w + 16*u + n16;
#pragma unroll
            for (int q=0; q<8; ++q)
                bh[g*2+u][q] = ld8f(whhp + (size_t)row*256 + q*32 + quad*8);
        }

        char* gb   = (char*)smem_;            // gate slots: [3][32768 B]
        u16*  hbuf = (u16*)(gb + 98304);      // [2][16][264] bf16
        for (int i=tid; i<8448; i+=512) hbuf[i] = 0;   // h(-1)=0 (both slots)

        u32* gtp = tags + s*32;
        u32* htp = tags + 256 + s*512;

        // prologue: stage gates(0) and gates(1)
        {
            int gd=0;
            while (ALD(gtp + 0) != 1u){ if(++gd>3000000) break; __builtin_amdgcn_s_sleep(2); }
            const char* sg = (const char*)(gring + (size_t)(s*32)*GSLOT_U64);
#pragma unroll
            for (int r=0; r<4; ++r) dma16(sg + (r*512+tid)*16, gb + (r*512+tid)*16);
            gd=0;
            while (ALD(gtp + 1) != 2u){ if(++gd>3000000) break; __builtin_amdgcn_s_sleep(2); }
            sg = (const char*)(gring + (size_t)(s*32 + 1)*GSLOT_U64);
#pragma unroll
            for (int r=0; r<4; ++r) dma16(sg + (r*512+tid)*16, gb + 32768 + (r*512+tid)*16);
            wait_vm0(); lgkm_barrier();
        }

        for (int t=0; t<SEQ; ++t) {
            // A: tags. h(t-2) data drained by end of step t-1 (vmcnt partial).
            if (tid==0) {
                AST(cparr + s, (u32)(t+1));
                if (s<=4 && t>=2) AST(htp + (t-2), (u32)(t-1));
            }
            // early poll of gtag(t+2); value consumed at phase F
            const bool need2 = (t+2 < SEQ);
            u32 tg2 = 0;
            if (need2) tg2 = ALD(gtp + ((t+2)&31));

            // B: publish h(t-1) / out(t-1) from LDS slot t&1
            const u16* hbP = hbuf + (t&1)*4224;
            if (t >= 1) {
                if (s<=4) {
                    if (tid < 256) {        // b = tid&15, 16B chunk k = tid>>4
                        const int b = tid & 15, k = tid >> 4;
                        char* hq = (char*)(hhb + (size_t)s*1048576 + (size_t)(t-1)*2048);
                        st16_sc1(hq + b*256 + k*16, *(const floatx4*)(hbP + b*264 + 8*k));
                    }
                } else {
                    const int off = (s==6)?256:0;
#pragma unroll
                    for (int k=0;k<5;++k) {
                        const int idx = tid + 512*k, b = idx >> 8, j = idx & 255;
                        if (b < 10)
                            out[(size_t)(t-1)*5120 + (size_t)b*512 + off + j] = bf2f(hbP[b*264 + j]);
                    }
                }
            }
            // D: acc init (r,z x-parts from slot t%3) + 48 MFMAs over K=256
            const char* g0 = gb + (t%3)*32768;
            floatx4 acc[6];
#pragma unroll
            for (int g=0; g<2; ++g)
#pragma unroll
            for (int u=0; u<2; ++u) {
                const int col = g*256 + 32*w + 16*u + n16;
                const u64 gw = *(const u64*)(g0 + col*32 + quad*8);
#pragma unroll
                for (int r=0; r<4; ++r) acc[g*2+u][r] = bf2f((u16)(gw >> (16*r)));
            }
            acc[4] = (floatx4){0.f,0.f,0.f,0.f};
            acc[5] = (floatx4){0.f,0.f,0.f,0.f};
#pragma unroll
            for (int q=0; q<8; ++q) {
                short8 ah = *(const short8*)(hbP + n16*264 + q*32 + quad*8);
#pragma unroll
                for (int m=0; m<6; ++m)
                    acc[m] = __builtin_amdgcn_mfma_f32_16x16x32_bf16(ah, bh[m][q], acc[m], 0,0,0);
            }
            // E: nonlinearity, h(t) -> LDS slot (t+1)&1
            u16* hbN = hbuf + ((t+1)&1)*4224;
            const float* nxp = (const float*)(g0 + 16384);
#pragma unroll
            for (int u=0; u<2; ++u) {
                const int j = 32*w + 16*u + n16;
                const floatx4 nx4 = *(const floatx4*)(nxp + j*16 + quad*4);
#pragma unroll
                for (int r=0; r<4; ++r) {
                    const int b = quad*4 + r;
                    float rr = sigmoidf_(acc[u][r]);
                    float zz = sigmoidf_(acc[2+u][r]);
                    float nn = tanhf_(nx4[r] + rr*acc[4+u][r]);
                    float hp = bf2f(hbP[b*264 + j]);
                    float hn = (1.0f-zz)*nn + zz*hp;
                    hbN[b*264 + j] = f2bf(hn);
                }
            }
            // F: issue DMA gates(t+2) -> slot (t+2)%3, then partial drain:
            // vmcnt(4) leaves ONLY the 4 fresh DMAs in flight; all older ops
            // (h/out stores, DMA(t+1)) complete before the barrier.
            if (need2) {
                if (tg2 != (u32)(t+3)) {
                    int gd=0;
                    while (ALD(gtp + ((t+2)&31)) != (u32)(t+3)){ if(++gd>3000000) break; __builtin_amdgcn_s_sleep(1); }
                }
                const char* sg = (const char*)(gring + (size_t)(s*32 + ((t+2)&31))*GSLOT_U64);
                char* dg = gb + ((t+2)%3)*32768;
#pragma unroll
                for (int r=0; r<4; ++r) dma16(sg + (r*512+tid)*16, dg + (r*512+tid)*16);
                wait_vm4();
            } else {
                wait_vm0();
            }
            lgkm_barrier();
        }
        // epilogue: h(511)/out(511) live in slot (512&1)=0
        const u16* hbL = hbuf;
        if (s<=4) {
            if (tid < 256) {
                const int b = tid & 15, k = tid >> 4;
                char* hq = (char*)(hhb + (size_t)s*1048576 + (size_t)(SEQ-1)*2048);
                st16_sc1(hq + b*256 + k*16, *(const floatx4*)(hbL + b*264 + 8*k));
            }
        } else {
            const int off = (s==6)?256:0;
#pragma unroll
            for (int k=0;k<5;++k) {
                const int idx = tid + 512*k, b = idx >> 8, j = idx & 255;
                if (b < 10)
                    out[(size_t)(SEQ-1)*5120 + (size_t)b*512 + off + j] = bf2f(hbL[b*264 + j]);
            }
        }
        wait_vm0(); lgkm_barrier();
        if (tid==0 && s<=4) { AST(htp + 510, 511u); AST(htp + 511, 512u); }
        // scan 6 is the last finisher: release the burners (monotonic bump)
        if (tid==0 && s==6)
            __hip_atomic_fetch_add(tags + DONE_OFF, 1u,
                                   __ATOMIC_RELAXED, __HIP_MEMORY_SCOPE_AGENT);
        return;
    }

    // ================= HELPERS: gates_x producers (3 WGs/stream) =================
    int sh, t0;
    if (blk < 10)      { sh = 0;               t0 = blk - 7;      }
    else if (blk < 25) { sh = 1 + (blk-10)/3;  t0 = (blk-10)%3;   }
    else               { sh = 6;               t0 = blk - 25;     }

    const int layer = (sh==6)?5:sh, dir=(sh==6)?1:0;
    const float* wihp; int stride;
    if (layer==0){ wihp = wihl0 + (size_t)dir*768*128; stride=128; }
    else         { wihp = wihrest + ((size_t)((layer-1)*2+dir))*768*512; stride=512; }

    // 8 waves x 6 tiles: gate col = (w*6+i)*16 + n16
    short8 bxf[6][4];
#pragma unroll
    for (int i=0; i<6; ++i) {
        const int col = (w*6+i)*16 + n16;
#pragma unroll
        for (int q=0; q<4; ++q)
            bxf[i][q] = ld8f(wihp + (size_t)col*stride + q*32 + quad*8);
    }
    char* tb = (char*)smem_;               // 32 KB slot image
    const int bmA = (n16>9)?9:n16;
    const int lsrc = (sh==6)? 4 : (sh-1);
    u32* gtp_sh = tags + sh*32;

    // Software-pipelined publish: slot t's 16B sc1 stores are issued at
    // iteration t; its tag is published at iteration t+3 after wait_vm0 +
    // barrier (store-ack overlaps the next slot's load+MFMA).
    int tprev = -1;
    for (int t = t0; t < SEQ; t += 3) {
        if (t >= 32) {   // ring-32 flow control vs consumer scan (lead <= 24)
            int gd=0;
            while ((int)ALD(cparr + sh) < t-24){ if(++gd>1000000) break; __builtin_amdgcn_s_sleep(8); }
        }
        if (tprev >= 0) {
            wait_vm0();            // own wave's slot-(tprev) stores acked
            __syncthreads();       // all waves acked (+ all tb readers done)
            if (tid==0) AST(gtp_sh + (tprev&31), (u32)(tprev+1));
        }
        short8 ax[4];
        if (sh == 0) {
            const float* xr = x + (size_t)t*1280 + (size_t)bmA*128;
#pragma unroll
            for (int q=0; q<4; ++q) ax[q] = ld8f(xr + q*32 + quad*8);
        } else {
            const int srct = (sh==6)? (SEQ-1-t) : t;
            int gd=0;
            while (ALD(tags + 256 + lsrc*512 + srct) != (u32)(srct+1)){ if(++gd>3000000) break; __builtin_amdgcn_s_sleep(4); }
            const u64* hq = (const u64*)(hhb + (size_t)lsrc*1048576 + (size_t)srct*2048);
#pragma unroll
            for (int q=0; q<4; ++q) {
                u64 a = ALD(hq + n16*32 + q*8 + quad*2);
                u64 b = ALD(hq + n16*32 + q*8 + quad*2 + 1);
                ax[q] = pk2(a, b);
            }
        }
        floatx4 acc[6];
#pragma unroll
        for (int i=0; i<6; ++i) acc[i] = (floatx4){0.f,0.f,0.f,0.f};
#pragma unroll
        for (int q=0; q<4; ++q)
#pragma unroll
            for (int i=0; i<6; ++i)
                acc[i] = __builtin_amdgcn_mfma_f32_16x16x32_bf16(ax[q], bxf[i][q], acc[i], 0,0,0);

        // slot image in LDS: rz bf16 [col<512][16], nx f32 [col-512][16]
        // (tb overwrite is safe: the tag barrier above drained all readers)
#pragma unroll
        for (int i=0; i<6; ++i) {
            const int col = (w*6+i)*16 + n16;
            if (col < 512) *(u64*)(tb + col*32 + quad*8) = pack4bf(acc[i]);
            else           *(floatx4*)(tb + 16384 + (col-512)*64 + quad*16) = acc[i];
        }
        __syncthreads();
        // publish 32KB slot: 4x 16B sc1 stores per thread
        char* gq = (char*)(gring + (size_t)(sh*32 + (t&31))*GSLOT_U64);
#pragma unroll
        for (int k=0;k<4;++k)
            st16_sc1(gq + tid*64 + k*16, *(const floatx4*)((const char*)tb + tid*64 + k*16));
        tprev = t;
    }
    wait_vm0(); __syncthreads();
    if (tid==0 && tprev>=0) AST(gtp_sh + (tprev&31), (u32)(tprev+1));
}

extern "C" void kernel_launch(void* const* d_in, const int* in_sizes, int n_in,
                              void* d_out, int out_size, void* d_ws, size_t ws_size,
                              hipStream_t stream) {
    (void)in_sizes; (void)n_in; (void)out_size; (void)ws_size;
    const float* x       = (const float*)d_in[0];
    const float* wihl0   = (const float*)d_in[1];
    const float* wihrest = (const float*)d_in[2];
    const float* whh     = (const float*)d_in[3];
    float* out = (float*)d_out;
    u64* gring = (u64*)d_ws;
    u16* hhb   = (u16*)((char*)d_ws + (size_t)GRING_U64*8);
    u32* tags  = (u32*)((char*)d_ws + TAGS_OFF_B);

    // No memset: 0xAAAAAAAA poison never equals a valid tag (1..512);
    // flow-control reads cast to int (poison negative => "not yet").
    // done-counter at tags+3072 is monotonic (fetch_add) => poison-safe and
    // replay-safe: burners exit on CHANGE from their captured start value.
    gru_pipeline<<<dim3(228), dim3(512), 0, stream>>>(x, wihl0, wihrest, whh, out,
                                                      gring, hhb, tags);
}

// Round 5
// 3386.494 us; speedup vs baseline: 1.2835x; 1.2138x over previous
//
#include <hip/hip_runtime.h>
#include <stdint.h>

// Bidirectional GRU, 6 layers, H=256, S=512, B=10, fp32 in/out, bf16 MFMA.
// 7 live scans + 21 helper WGs (3/stream), gates via global_load_lds (SC1).
// THIS ROUND — remove ALL same-step device-scope drains from the scan loop:
//   r0-r4 invariance (3 transports within 8%, clock burners null) => limiter
//   is the per-step forced drain set shared by all rounds: (a) gtag ALD
//   branch-consumed same step (compiler vmcnt drains everything), (b) h-store
//   retired by wait_vm4 same step, (c) tid0 tag ASTs ditto.
//   1) LDS tag mirror: wave0 DMAs gtag(t+4) into LDS at F(t); validity of
//      slot t+2 checked at F(t) from a 2-step-old LDS word (zero RTT).
//      Watertight: mirror==t+3 => helper tag @MALL before mirror-read service
//      => gate data (helper vm0 before tag) @MALL before our data DMA reads.
//      Mismatch -> rare global poll slow path.
//   2) Exact per-wave counted vmcnt at F (readfirstlane wave-uniform
//      branches): every VMEM op gets >=1.7 steps of slack. htag shifted to
//      (t-3): h(t-3) stored B(t-2), drained F(t-1), published A(t).
//   3) VALU diet: IEEE divides (24/thread/step) -> v_rcp_f32; fma-form h;
//      float4 out-stores for s5/s6.
// Helpers byte-identical to round 1. No burners (grid 28).

typedef short short8 __attribute__((ext_vector_type(8)));
typedef float floatx4 __attribute__((ext_vector_type(4)));
typedef unsigned long long u64;
typedef unsigned int u32;
typedef unsigned short u16;

#define SEQ 512

// ws: gring 7*32 slots x 32KB (rz bf16 [512][16] + nx f32 [256][16]) = 7.34MB
//     hh   scans 0..4 [t:512][b:16][ch:128] bf16 = 10.5MB
//     tags u32: gtag[7][32] @0 ; htag[5][512] @256 ; cparr[7] @2816
#define GSLOT_U64 4096
#define GRING_U64 (7 * 32 * GSLOT_U64)
#define HH_U16 (5 * 512 * 2048)
#define TAGS_OFF_B ((size_t)GRING_U64 * 8 + (size_t)HH_U16 * 2)

__device__ __forceinline__ u16 f2bf(float f){ union{float f;u32 i;}v; v.f=f; u32 u=v.i; u += 0x7fffu + ((u>>16)&1u); return (u16)(u>>16); }
__device__ __forceinline__ float bf2f(u16 h){ union{u32 i;float f;}v; v.i=((u32)h)<<16; return v.f; }
__device__ __forceinline__ short8 ld8f(const float* p){
    float4 a=*(const float4*)p, b=*(const float4*)(p+4);
    short8 r; r[0]=(short)f2bf(a.x); r[1]=(short)f2bf(a.y); r[2]=(short)f2bf(a.z); r[3]=(short)f2bf(a.w);
    r[4]=(short)f2bf(b.x); r[5]=(short)f2bf(b.y); r[6]=(short)f2bf(b.z); r[7]=(short)f2bf(b.w); return r;
}
__device__ __forceinline__ short8 pk2(u64 a, u64 b){ union{u64 q[2]; short8 s;}v; v.q[0]=a; v.q[1]=b; return v.s; }
__device__ __forceinline__ u64 pack4bf(floatx4 a){
    return (u64)f2bf(a[0]) | ((u64)f2bf(a[1])<<16) | ((u64)f2bf(a[2])<<32) | ((u64)f2bf(a[3])<<48);
}
// fast reciprocal (v_rcp_f32, ~1 ulp; tolerance is 4.9e-4 with bf16 noise)
__device__ __forceinline__ float rcp_(float x){ float r; asm("v_rcp_f32 %0, %1" : "=v"(r) : "v"(x)); return r; }
__device__ __forceinline__ float sigmoidf_(float x){ return rcp_(1.0f + __expf(-x)); }
__device__ __forceinline__ float tanhf_(float x){ return 1.0f - 2.0f*rcp_(__expf(2.0f*x) + 1.0f); }

#define ALD(p)    __hip_atomic_load((p), __ATOMIC_RELAXED, __HIP_MEMORY_SCOPE_AGENT)
#define AST(p,v)  __hip_atomic_store((p),(v),__ATOMIC_RELAXED,__HIP_MEMORY_SCOPE_AGENT)
__device__ __forceinline__ void wait_vm0(){ asm volatile("s_waitcnt vmcnt(0)" ::: "memory"); }
#define WVC(n) asm volatile("s_waitcnt vmcnt(" #n ")" ::: "memory")
__device__ __forceinline__ void lgkm_barrier(){ asm volatile("s_waitcnt lgkmcnt(0)\n\ts_barrier" ::: "memory"); }

// 16B device-scope (MALL-visible) store: sc1 cache policy at dwordx4 width.
__device__ __forceinline__ void st16_sc1(void* p, floatx4 v){
    asm volatile("global_store_dwordx4 %0, %1, off sc1" :: "v"(p), "v"(v) : "memory");
}

// global->LDS DMA, SC1 (device-scope, bypass per-XCD L2)
__device__ __forceinline__ void dma16(const void* g, void* l) {
    __builtin_amdgcn_global_load_lds(
        reinterpret_cast<const __attribute__((address_space(1))) unsigned int*>(
            (uintptr_t)g),
        reinterpret_cast<__attribute__((address_space(3))) unsigned int*>(
            (uintptr_t)l), 16, 0, 16);
}
__device__ __forceinline__ void dma4(const void* g, void* l) {
    __builtin_amdgcn_global_load_lds(
        reinterpret_cast<const __attribute__((address_space(1))) unsigned int*>(
            (uintptr_t)g),
        reinterpret_cast<__attribute__((address_space(3))) unsigned int*>(
            (uintptr_t)l), 4, 0, 16);
}

__global__ __launch_bounds__(512, 2)
void gru_pipeline(const float* __restrict__ x,
                  const float* __restrict__ wihl0,
                  const float* __restrict__ wihrest,
                  const float* __restrict__ whh,
                  float* __restrict__ out,
                  u64* __restrict__ gring,
                  u16* __restrict__ hhb,
                  u32* __restrict__ tags)
{
    __shared__ u64 smem_[14404];   // 115,232 B: gbuf 3x32768 + hbuf 16,896 + tagmir 16
    const int blk  = blockIdx.x;
    const int tid  = threadIdx.x;
    const int w    = tid >> 6;
    const int lane = tid & 63;
    const int n16  = lane & 15;
    const int quad = lane >> 4;
    u32* cparr = tags + 2816;

    if (blk < 7) {
        // ================= SCAN: one 512-thread WG per scan =================
        const int s = blk;
        const int wu = __builtin_amdgcn_readfirstlane(tid) >> 6;   // wave idx, SGPR
        const int layer = (s==6)?5:s, dir=(s==6)?1:0;
        const float* whhp = whh + ((size_t)(layer*2+dir))*768*256;

        // W_hh B-frags: wave owns units j in [32w,32w+32): tiles m=g*2+u
        short8 bh[6][8];
#pragma unroll
        for (int g=0; g<3; ++g)
#pragma unroll
        for (int u=0; u<2; ++u) {
            const int row = g*256 + 32*w + 16*u + n16;
#pragma unroll
            for (int q=0; q<8; ++q)
                bh[g*2+u][q] = ld8f(whhp + (size_t)row*256 + q*32 + quad*8);
        }

        char* gb   = (char*)smem_;                      // gate slots: [3][32768 B]
        u16*  hbuf = (u16*)(gb + 98304);                // [2][16][264] bf16
        u32*  tagmir = (u32*)((char*)smem_ + 115200);   // [4] gtag mirror ring
        for (int i=tid; i<8448; i+=512) hbuf[i] = 0;    // h(-1)=0 (both slots)

        u32* gtp = tags + s*32;
        u32* htp = tags + 256 + s*512;

        // prologue: stage gates(0), gates(1); mirror tags for slots 2,3
        {
            int gd=0;
            while (ALD(gtp + 0) != 1u){ if(++gd>3000000) break; __builtin_amdgcn_s_sleep(2); }
            const char* sg = (const char*)(gring + (size_t)(s*32)*GSLOT_U64);
#pragma unroll
            for (int r=0; r<4; ++r) dma16(sg + (r*512+tid)*16, gb + (r*512+tid)*16);
            gd=0;
            while (ALD(gtp + 1) != 2u){ if(++gd>3000000) break; __builtin_amdgcn_s_sleep(2); }
            sg = (const char*)(gring + (size_t)(s*32 + 1)*GSLOT_U64);
#pragma unroll
            for (int r=0; r<4; ++r) dma16(sg + (r*512+tid)*16, gb + 32768 + (r*512+tid)*16);
            if (tid==0) { dma4(gtp + 2, tagmir + 2); dma4(gtp + 3, tagmir + 3); }
            wait_vm0(); lgkm_barrier();
        }

        for (int t=0; t<SEQ; ++t) {
            // A: tags (wave0 all-lanes, same addr/value; scalar-branch skip on w1-7).
            // htag(t-3): h(t-3) stored B(t-2), drained F(t-1) => data-before-tag.
            if (wu == 0) {
                if ((t&3)==0) AST(cparr + s, (u32)(t+1));
                if (s<=4 && t>=3) AST(htp + (t-3), (u32)(t-2));
            }

            // B: publish h(t-1) / out(t-1) from LDS slot t&1
            const u16* hbP = hbuf + (t&1)*4224;
            if (t >= 1) {
                if (s<=4) {
                    if (wu < 4) {       // tid<256: b = tid&15, 16B chunk k = tid>>4
                        const int b = tid & 15, k = (tid >> 4) & 15;
                        char* hq = (char*)(hhb + (size_t)s*1048576 + (size_t)(t-1)*2048);
                        st16_sc1(hq + b*256 + k*16, *(const floatx4*)(hbP + b*264 + 8*k));
                    }
                } else {
                    const int off = (s==6)?256:0;
                    {   // store 0: all 512 threads
                        const int b = tid >> 6, jg = (tid & 63)*4;
                        union { u64 q; u16 h[4]; } v; v.q = *(const u64*)(hbP + b*264 + jg);
                        float4 o; o.x=bf2f(v.h[0]); o.y=bf2f(v.h[1]); o.z=bf2f(v.h[2]); o.w=bf2f(v.h[3]);
                        *(float4*)(out + (size_t)(t-1)*5120 + (size_t)b*512 + off + jg) = o;
                    }
                    if (wu < 2) {   // store 1: tids 0-127 (idx 512..639)
                        const int idx = tid + 512;
                        const int b = idx >> 6, jg = (idx & 63)*4;
                        union { u64 q; u16 h[4]; } v; v.q = *(const u64*)(hbP + b*264 + jg);
                        float4 o; o.x=bf2f(v.h[0]); o.y=bf2f(v.h[1]); o.z=bf2f(v.h[2]); o.w=bf2f(v.h[3]);
                        *(float4*)(out + (size_t)(t-1)*5120 + (size_t)b*512 + off + jg) = o;
                    }
                }
            }
            // D: acc init (r,z x-parts from slot t%3) + 48 MFMAs over K=256
            const char* g0 = gb + (t%3)*32768;
            floatx4 acc[6];
#pragma unroll
            for (int g=0; g<2; ++g)
#pragma unroll
            for (int u=0; u<2; ++u) {
                const int col = g*256 + 32*w + 16*u + n16;
                const u64 gw = *(const u64*)(g0 + col*32 + quad*8);
#pragma unroll
                for (int r=0; r<4; ++r) acc[g*2+u][r] = bf2f((u16)(gw >> (16*r)));
            }
            acc[4] = (floatx4){0.f,0.f,0.f,0.f};
            acc[5] = (floatx4){0.f,0.f,0.f,0.f};
#pragma unroll
            for (int q=0; q<8; ++q) {
                short8 ah = *(const short8*)(hbP + n16*264 + q*32 + quad*8);
#pragma unroll
                for (int m=0; m<6; ++m)
                    acc[m] = __builtin_amdgcn_mfma_f32_16x16x32_bf16(ah, bh[m][q], acc[m], 0,0,0);
            }
            // E: nonlinearity (rcp-based), h(t) -> LDS slot (t+1)&1
            u16* hbN = hbuf + ((t+1)&1)*4224;
            const float* nxp = (const float*)(g0 + 16384);
#pragma unroll
            for (int u=0; u<2; ++u) {
                const int j = 32*w + 16*u + n16;
                const floatx4 nx4 = *(const floatx4*)(nxp + j*16 + quad*4);
#pragma unroll
                for (int r=0; r<4; ++r) {
                    const int b = quad*4 + r;
                    float rr = sigmoidf_(acc[u][r]);
                    float zz = sigmoidf_(acc[2+u][r]);
                    float nn = tanhf_(nx4[r] + rr*acc[4+u][r]);
                    float hp = bf2f(hbP[b*264 + j]);
                    float hn = nn + zz*(hp - nn);
                    hbN[b*264 + j] = f2bf(hn);
                }
            }
            // F: validity of slot t+2 via LDS tag mirror (2-step-old), issue
            // dma(t+2) + mirror-dma(t+4), then exact per-wave counted drain:
            // keep ONLY this step's ops in flight (everything gets >=1.7 steps).
            bool slow = false;
            if (t+2 < SEQ) {
                if (tagmir[(t+2)&3] != (u32)(t+3)) {    // rare: helper late / warm-up
                    int gd=0;
                    while (ALD(gtp + ((t+2)&31)) != (u32)(t+3)){ if(++gd>3000000) break; __builtin_amdgcn_s_sleep(1); }
                    slow = true;
                }
                const char* sg = (const char*)(gring + (size_t)(s*32 + ((t+2)&31))*GSLOT_U64);
                char* dg = gb + ((t+2)%3)*32768;
#pragma unroll
                for (int r=0; r<4; ++r) dma16(sg + (r*512+tid)*16, dg + (r*512+tid)*16);
                if (t+4 < SEQ && wu==0) {
                    if (lane==0) dma4(gtp + ((t+4)&31), tagmir + ((t+4)&3));
                }
            }
            if (slow || t < 4 || t >= SEQ-4) {
                wait_vm0();
            } else if (wu == 0) {            // htag/cparr + H + D4 + tagdma
                if ((t&3)==0) { WVC(8); } else { WVC(7); }
            } else if (s <= 4) {
                if (wu < 4) { WVC(5); } else { WVC(4); }   // H + D4 / D4
            } else {
                if (wu == 1) { WVC(6); } else { WVC(5); }  // out2+D4 / out1+D4
            }
            lgkm_barrier();
        }
        // epilogue: h(511)/out(511) live in slot (512&1)=0
        const u16* hbL = hbuf;
        if (s<=4) {
            if (wu < 4) {
                const int b = tid & 15, k = (tid >> 4) & 15;
                char* hq = (char*)(hhb + (size_t)s*1048576 + (size_t)(SEQ-1)*2048);
                st16_sc1(hq + b*256 + k*16, *(const floatx4*)(hbL + b*264 + 8*k));
            }
        } else {
            const int off = (s==6)?256:0;
            {
                const int b = tid >> 6, jg = (tid & 63)*4;
                union { u64 q; u16 h[4]; } v; v.q = *(const u64*)(hbL + b*264 + jg);
                float4 o; o.x=bf2f(v.h[0]); o.y=bf2f(v.h[1]); o.z=bf2f(v.h[2]); o.w=bf2f(v.h[3]);
                *(float4*)(out + (size_t)(SEQ-1)*5120 + (size_t)b*512 + off + jg) = o;
            }
            if (wu < 2) {
                const int idx = tid + 512;
                const int b = idx >> 6, jg = (idx & 63)*4;
                union { u64 q; u16 h[4]; } v; v.q = *(const u64*)(hbL + b*264 + jg);
                float4 o; o.x=bf2f(v.h[0]); o.y=bf2f(v.h[1]); o.z=bf2f(v.h[2]); o.w=bf2f(v.h[3]);
                *(float4*)(out + (size_t)(SEQ-1)*5120 + (size_t)b*512 + off + jg) = o;
            }
        }
        wait_vm0(); lgkm_barrier();
        if (tid==0 && s<=4) { AST(htp + 509, 510u); AST(htp + 510, 511u); AST(htp + 511, 512u); }
        return;
    }

    // ================= HELPERS: gates_x producers (3 WGs/stream) =================
    int sh, t0;
    if (blk < 10)      { sh = 0;               t0 = blk - 7;      }
    else if (blk < 25) { sh = 1 + (blk-10)/3;  t0 = (blk-10)%3;   }
    else               { sh = 6;               t0 = blk - 25;     }

    const int layer = (sh==6)?5:sh, dir=(sh==6)?1:0;
    const float* wihp; int stride;
    if (layer==0){ wihp = wihl0 + (size_t)dir*768*128; stride=128; }
    else         { wihp = wihrest + ((size_t)((layer-1)*2+dir))*768*512; stride=512; }

    // 8 waves x 6 tiles: gate col = (w*6+i)*16 + n16
    short8 bxf[6][4];
#pragma unroll
    for (int i=0; i<6; ++i) {
        const int col = (w*6+i)*16 + n16;
#pragma unroll
        for (int q=0; q<4; ++q)
            bxf[i][q] = ld8f(wihp + (size_t)col*stride + q*32 + quad*8);
    }
    char* tb = (char*)smem_;               // 32 KB slot image
    const int bmA = (n16>9)?9:n16;
    const int lsrc = (sh==6)? 4 : (sh-1);
    u32* gtp_sh = tags + sh*32;

    // Software-pipelined publish: slot t's 16B sc1 stores issued at iter t;
    // tag published at iter t+3 after wait_vm0 + barrier.
    int tprev = -1;
    for (int t = t0; t < SEQ; t += 3) {
        if (t >= 32) {   // ring-32 flow control vs consumer scan (lead <= 24)
            int gd=0;
            while ((int)ALD(cparr + sh) < t-24){ if(++gd>1000000) break; __builtin_amdgcn_s_sleep(8); }
        }
        if (tprev >= 0) {
            wait_vm0();            // own wave's slot-(tprev) stores acked
            __syncthreads();       // all waves acked (+ all tb readers done)
            if (tid==0) AST(gtp_sh + (tprev&31), (u32)(tprev+1));
        }
        short8 ax[4];
        if (sh == 0) {
            const float* xr = x + (size_t)t*1280 + (size_t)bmA*128;
#pragma unroll
            for (int q=0; q<4; ++q) ax[q] = ld8f(xr + q*32 + quad*8);
        } else {
            const int srct = (sh==6)? (SEQ-1-t) : t;
            int gd=0;
            while (ALD(tags + 256 + lsrc*512 + srct) != (u32)(srct+1)){ if(++gd>3000000) break; __builtin_amdgcn_s_sleep(4); }
            const u64* hq = (const u64*)(hhb + (size_t)lsrc*1048576 + (size_t)srct*2048);
#pragma unroll
            for (int q=0; q<4; ++q) {
                u64 a = ALD(hq + n16*32 + q*8 + quad*2);
                u64 b = ALD(hq + n16*32 + q*8 + quad*2 + 1);
                ax[q] = pk2(a, b);
            }
        }
        floatx4 acc[6];
#pragma unroll
        for (int i=0; i<6; ++i) acc[i] = (floatx4){0.f,0.f,0.f,0.f};
#pragma unroll
        for (int q=0; q<4; ++q)
#pragma unroll
            for (int i=0; i<6; ++i)
                acc[i] = __builtin_amdgcn_mfma_f32_16x16x32_bf16(ax[q], bxf[i][q], acc[i], 0,0,0);

        // slot image in LDS: rz bf16 [col<512][16], nx f32 [col-512][16]
        // (tb overwrite is safe: the tag barrier above drained all readers)
#pragma unroll
        for (int i=0; i<6; ++i) {
            const int col = (w*6+i)*16 + n16;
            if (col < 512) *(u64*)(tb + col*32 + quad*8) = pack4bf(acc[i]);
            else           *(floatx4*)(tb + 16384 + (col-512)*64 + quad*16) = acc[i];
        }
        __syncthreads();
        // publish 32KB slot: 4x 16B sc1 stores per thread
        char* gq = (char*)(gring + (size_t)(sh*32 + (t&31))*GSLOT_U64);
#pragma unroll
        for (int k=0;k<4;++k)
            st16_sc1(gq + tid*64 + k*16, *(const floatx4*)((const char*)tb + tid*64 + k*16));
        tprev = t;
    }
    wait_vm0(); __syncthreads();
    if (tid==0 && tprev>=0) AST(gtp_sh + (tprev&31), (u32)(tprev+1));
}

extern "C" void kernel_launch(void* const* d_in, const int* in_sizes, int n_in,
                              void* d_out, int out_size, void* d_ws, size_t ws_size,
                              hipStream_t stream) {
    (void)in_sizes; (void)n_in; (void)out_size; (void)ws_size;
    const float* x       = (const float*)d_in[0];
    const float* wihl0   = (const float*)d_in[1];
    const float* wihrest = (const float*)d_in[2];
    const float* whh     = (const float*)d_in[3];
    float* out = (float*)d_out;
    u64* gring = (u64*)d_ws;
    u16* hhb   = (u16*)((char*)d_ws + (size_t)GRING_U64*8);
    u32* tags  = (u32*)((char*)d_ws + TAGS_OFF_B);

    // No memset: 0xAAAAAAAA poison never equals a valid tag (1..512);
    // flow-control reads cast to int (poison negative => "not yet");
    // LDS tag mirrors hold stale-generation values (t-1 != t+3) => slow path.
    gru_pipeline<<<dim3(28), dim3(512), 0, stream>>>(x, wihl0, wihrest, whh, out,
                                                     gring, hhb, tags);
}

// Round 6
// 3371.445 us; speedup vs baseline: 1.2892x; 1.0045x over previous
//
#include <hip/hip_runtime.h>
#include <stdint.h>

// Bidirectional GRU, 6 layers, H=256, S=512, B=10, fp32 in/out, bf16 MFMA.
// 7 live scans + 21 helper WGs (3/stream), gates via global_load_lds (SC1).
// THIS ROUND — double the gate-DMA in-flight slack (1.0 -> ~1.9 steps):
//   Round-5 (-16%) confirmed same-step drains were binding. Residual: dma(t+2)
//   issued at F(t), force-drained at F(t+1) = 1.0 step slack => step ~= DMA
//   RTT (~3.3us). Fix: issue dma(t+2) at A(t) (post-barrier; slot's previous
//   readers are barrier-separated) with drain still at F(t+1).
//   - A order: ASTs -> tagdma(t+4) -> dma(t+2)x4. Exact keep counts (provable
//     minimum of newer ops; undercount safe, overcount racy):
//     s<=4 {w0:8, w1-3:6, w4-7:4}; s5/6 {w0:9, w1:8, w2-7:6}.
//   - htag shift t-3 -> t-4 (hstore(t-4) provably drained by F(t-1) before
//     A(t) publication); epilogue publishes 508..511.
//   - edges t<4, t>=SEQ-5: wait_vm0 (steady counts invalid there).
// Helpers byte-identical to rounds 1/5 (proven). LDS 115,232 B unchanged.

typedef short short8 __attribute__((ext_vector_type(8)));
typedef float floatx4 __attribute__((ext_vector_type(4)));
typedef unsigned long long u64;
typedef unsigned int u32;
typedef unsigned short u16;

#define SEQ 512

// ws: gring 7*32 slots x 32KB (rz bf16 [512][16] + nx f32 [256][16]) = 7.34MB
//     hh   scans 0..4 [t:512][b:16][ch:128] bf16 = 10.5MB
//     tags u32: gtag[7][32] @0 ; htag[5][512] @256 ; cparr[7] @2816
#define GSLOT_U64 4096
#define GRING_U64 (7 * 32 * GSLOT_U64)
#define HH_U16 (5 * 512 * 2048)
#define TAGS_OFF_B ((size_t)GRING_U64 * 8 + (size_t)HH_U16 * 2)

__device__ __forceinline__ u16 f2bf(float f){ union{float f;u32 i;}v; v.f=f; u32 u=v.i; u += 0x7fffu + ((u>>16)&1u); return (u16)(u>>16); }
__device__ __forceinline__ float bf2f(u16 h){ union{u32 i;float f;}v; v.i=((u32)h)<<16; return v.f; }
__device__ __forceinline__ short8 ld8f(const float* p){
    float4 a=*(const float4*)p, b=*(const float4*)(p+4);
    short8 r; r[0]=(short)f2bf(a.x); r[1]=(short)f2bf(a.y); r[2]=(short)f2bf(a.z); r[3]=(short)f2bf(a.w);
    r[4]=(short)f2bf(b.x); r[5]=(short)f2bf(b.y); r[6]=(short)f2bf(b.z); r[7]=(short)f2bf(b.w); return r;
}
__device__ __forceinline__ short8 pk2(u64 a, u64 b){ union{u64 q[2]; short8 s;}v; v.q[0]=a; v.q[1]=b; return v.s; }
__device__ __forceinline__ u64 pack4bf(floatx4 a){
    return (u64)f2bf(a[0]) | ((u64)f2bf(a[1])<<16) | ((u64)f2bf(a[2])<<32) | ((u64)f2bf(a[3])<<48);
}
// fast reciprocal (v_rcp_f32, ~1 ulp; validated round 5: absmax unchanged)
__device__ __forceinline__ float rcp_(float x){ float r; asm("v_rcp_f32 %0, %1" : "=v"(r) : "v"(x)); return r; }
__device__ __forceinline__ float sigmoidf_(float x){ return rcp_(1.0f + __expf(-x)); }
__device__ __forceinline__ float tanhf_(float x){ return 1.0f - 2.0f*rcp_(__expf(2.0f*x) + 1.0f); }

#define ALD(p)    __hip_atomic_load((p), __ATOMIC_RELAXED, __HIP_MEMORY_SCOPE_AGENT)
#define AST(p,v)  __hip_atomic_store((p),(v),__ATOMIC_RELAXED,__HIP_MEMORY_SCOPE_AGENT)
__device__ __forceinline__ void wait_vm0(){ asm volatile("s_waitcnt vmcnt(0)" ::: "memory"); }
#define WVC(n) asm volatile("s_waitcnt vmcnt(" #n ")" ::: "memory")
__device__ __forceinline__ void lgkm_barrier(){ asm volatile("s_waitcnt lgkmcnt(0)\n\ts_barrier" ::: "memory"); }

// 16B device-scope (MALL-visible) store: sc1 cache policy at dwordx4 width.
__device__ __forceinline__ void st16_sc1(void* p, floatx4 v){
    asm volatile("global_store_dwordx4 %0, %1, off sc1" :: "v"(p), "v"(v) : "memory");
}

// global->LDS DMA, SC1 (device-scope, bypass per-XCD L2)
__device__ __forceinline__ void dma16(const void* g, void* l) {
    __builtin_amdgcn_global_load_lds(
        reinterpret_cast<const __attribute__((address_space(1))) unsigned int*>(
            (uintptr_t)g),
        reinterpret_cast<__attribute__((address_space(3))) unsigned int*>(
            (uintptr_t)l), 16, 0, 16);
}
__device__ __forceinline__ void dma4(const void* g, void* l) {
    __builtin_amdgcn_global_load_lds(
        reinterpret_cast<const __attribute__((address_space(1))) unsigned int*>(
            (uintptr_t)g),
        reinterpret_cast<__attribute__((address_space(3))) unsigned int*>(
            (uintptr_t)l), 4, 0, 16);
}

__global__ __launch_bounds__(512, 2)
void gru_pipeline(const float* __restrict__ x,
                  const float* __restrict__ wihl0,
                  const float* __restrict__ wihrest,
                  const float* __restrict__ whh,
                  float* __restrict__ out,
                  u64* __restrict__ gring,
                  u16* __restrict__ hhb,
                  u32* __restrict__ tags)
{
    __shared__ u64 smem_[14404];   // 115,232 B: gbuf 3x32768 + hbuf 16,896 + tagmir 16
    const int blk  = blockIdx.x;
    const int tid  = threadIdx.x;
    const int w    = tid >> 6;
    const int lane = tid & 63;
    const int n16  = lane & 15;
    const int quad = lane >> 4;
    u32* cparr = tags + 2816;

    if (blk < 7) {
        // ================= SCAN: one 512-thread WG per scan =================
        const int s = blk;
        const int wu = __builtin_amdgcn_readfirstlane(tid) >> 6;   // wave idx, SGPR
        const int layer = (s==6)?5:s, dir=(s==6)?1:0;
        const float* whhp = whh + ((size_t)(layer*2+dir))*768*256;

        // W_hh B-frags: wave owns units j in [32w,32w+32): tiles m=g*2+u
        short8 bh[6][8];
#pragma unroll
        for (int g=0; g<3; ++g)
#pragma unroll
        for (int u=0; u<2; ++u) {
            const int row = g*256 + 32*w + 16*u + n16;
#pragma unroll
            for (int q=0; q<8; ++q)
                bh[g*2+u][q] = ld8f(whhp + (size_t)row*256 + q*32 + quad*8);
        }

        char* gb   = (char*)smem_;                      // gate slots: [3][32768 B]
        u16*  hbuf = (u16*)(gb + 98304);                // [2][16][264] bf16
        u32*  tagmir = (u32*)((char*)smem_ + 115200);   // [4] gtag mirror ring
        for (int i=tid; i<8448; i+=512) hbuf[i] = 0;    // h(-1)=0 (both slots)

        u32* gtp = tags + s*32;
        u32* htp = tags + 256 + s*512;

        // prologue: stage gates(0), gates(1); mirror tags for slots 2,3
        {
            int gd=0;
            while (ALD(gtp + 0) != 1u){ if(++gd>3000000) break; __builtin_amdgcn_s_sleep(2); }
            const char* sg = (const char*)(gring + (size_t)(s*32)*GSLOT_U64);
#pragma unroll
            for (int r=0; r<4; ++r) dma16(sg + (r*512+tid)*16, gb + (r*512+tid)*16);
            gd=0;
            while (ALD(gtp + 1) != 2u){ if(++gd>3000000) break; __builtin_amdgcn_s_sleep(2); }
            sg = (const char*)(gring + (size_t)(s*32 + 1)*GSLOT_U64);
#pragma unroll
            for (int r=0; r<4; ++r) dma16(sg + (r*512+tid)*16, gb + 32768 + (r*512+tid)*16);
            if (tid==0) { dma4(gtp + 2, tagmir + 2); dma4(gtp + 3, tagmir + 3); }
            wait_vm0(); lgkm_barrier();
        }

        for (int t=0; t<SEQ; ++t) {
            const u16* hbP = hbuf + (t&1)*4224;
            bool slow = false;
            // A (post-barrier): tags, mirror check, tagdma(t+4), dma(t+2).
            // Slot (t+2)%3's previous readers = D/E(t-1), barrier-separated.
            // htag(t-4): hstore(t-4)@B(t-3) provably drained by F(t-1).
            if (wu == 0) {
                if ((t&3)==0) AST(cparr + s, (u32)(t+1));
                if (s<=4 && t>=4) AST(htp + (t-4), (u32)(t-3));
            }
            if (t+2 < SEQ) {
                if (tagmir[(t+2)&3] != (u32)(t+3)) {    // rare: warm-up / helper late
                    int gd=0;
                    while (ALD(gtp + ((t+2)&31)) != (u32)(t+3)){ if(++gd>3000000) break; __builtin_amdgcn_s_sleep(1); }
                    slow = true;
                }
                if (wu==0 && lane==0 && t+4 < SEQ)
                    dma4(gtp + ((t+4)&31), tagmir + ((t+4)&3));
                const char* sg = (const char*)(gring + (size_t)(s*32 + ((t+2)&31))*GSLOT_U64);
                char* dg = gb + ((t+2)%3)*32768;
#pragma unroll
                for (int r=0; r<4; ++r) dma16(sg + (r*512+tid)*16, dg + (r*512+tid)*16);
            }

            // B: publish h(t-1) / out(t-1) from LDS slot t&1
            if (t >= 1) {
                if (s<=4) {
                    if (wu < 4) {       // tid<256: b = tid&15, 16B chunk k
                        const int b = tid & 15, k = (tid >> 4) & 15;
                        char* hq = (char*)(hhb + (size_t)s*1048576 + (size_t)(t-1)*2048);
                        st16_sc1(hq + b*256 + k*16, *(const floatx4*)(hbP + b*264 + 8*k));
                    }
                } else {
                    const int off = (s==6)?256:0;
                    {   // store 0: all 512 threads
                        const int b = tid >> 6, jg = (tid & 63)*4;
                        union { u64 q; u16 h[4]; } v; v.q = *(const u64*)(hbP + b*264 + jg);
                        float4 o; o.x=bf2f(v.h[0]); o.y=bf2f(v.h[1]); o.z=bf2f(v.h[2]); o.w=bf2f(v.h[3]);
                        *(float4*)(out + (size_t)(t-1)*5120 + (size_t)b*512 + off + jg) = o;
                    }
                    if (wu < 2) {   // store 1: tids 0-127 (idx 512..639)
                        const int idx = tid + 512;
                        const int b = idx >> 6, jg = (idx & 63)*4;
                        union { u64 q; u16 h[4]; } v; v.q = *(const u64*)(hbP + b*264 + jg);
                        float4 o; o.x=bf2f(v.h[0]); o.y=bf2f(v.h[1]); o.z=bf2f(v.h[2]); o.w=bf2f(v.h[3]);
                        *(float4*)(out + (size_t)(t-1)*5120 + (size_t)b*512 + off + jg) = o;
                    }
                }
            }
            // D: acc init (r,z x-parts from slot t%3) + 48 MFMAs over K=256
            const char* g0 = gb + (t%3)*32768;
            floatx4 acc[6];
#pragma unroll
            for (int g=0; g<2; ++g)
#pragma unroll
            for (int u=0; u<2; ++u) {
                const int col = g*256 + 32*w + 16*u + n16;
                const u64 gw = *(const u64*)(g0 + col*32 + quad*8);
#pragma unroll
                for (int r=0; r<4; ++r) acc[g*2+u][r] = bf2f((u16)(gw >> (16*r)));
            }
            acc[4] = (floatx4){0.f,0.f,0.f,0.f};
            acc[5] = (floatx4){0.f,0.f,0.f,0.f};
#pragma unroll
            for (int q=0; q<8; ++q) {
                short8 ah = *(const short8*)(hbP + n16*264 + q*32 + quad*8);
#pragma unroll
                for (int m=0; m<6; ++m)
                    acc[m] = __builtin_amdgcn_mfma_f32_16x16x32_bf16(ah, bh[m][q], acc[m], 0,0,0);
            }
            // E: nonlinearity (rcp-based), h(t) -> LDS slot (t+1)&1
            u16* hbN = hbuf + ((t+1)&1)*4224;
            const float* nxp = (const float*)(g0 + 16384);
#pragma unroll
            for (int u=0; u<2; ++u) {
                const int j = 32*w + 16*u + n16;
                const floatx4 nx4 = *(const floatx4*)(nxp + j*16 + quad*4);
#pragma unroll
                for (int r=0; r<4; ++r) {
                    const int b = quad*4 + r;
                    float rr = sigmoidf_(acc[u][r]);
                    float zz = sigmoidf_(acc[2+u][r]);
                    float nn = tanhf_(nx4[r] + rr*acc[4+u][r]);
                    float hp = bf2f(hbP[b*264 + j]);
                    float hn = nn + zz*(hp - nn);
                    hbN[b*264 + j] = f2bf(hn);
                }
            }
            // F: counted drain. Target: dma(t+1) (issued A(t-1), ~1.9 steps old)
            // + everything older. Keep = provable minimum of newer ops.
            if (slow || t < 4 || t >= SEQ-5) {
                wait_vm0();
            } else if (s <= 4) {
                if (wu == 0)      { WVC(8); }   // hst(t-2)+htag+tagdma+dma4+hst(t-1)
                else if (wu < 4)  { WVC(6); }   // hst(t-2)+dma4+hst(t-1)
                else              { WVC(4); }   // dma4
            } else {
                if (wu == 0)      { WVC(9); }   // out2+tagdma+dma4+out2
                else if (wu == 1) { WVC(8); }   // out2+dma4+out2
                else              { WVC(6); }   // out1+dma4+out1
            }
            lgkm_barrier();
        }
        // epilogue: h(511)/out(511) live in slot (512&1)=0
        const u16* hbL = hbuf;
        if (s<=4) {
            if (wu < 4) {
                const int b = tid & 15, k = (tid >> 4) & 15;
                char* hq = (char*)(hhb + (size_t)s*1048576 + (size_t)(SEQ-1)*2048);
                st16_sc1(hq + b*256 + k*16, *(const floatx4*)(hbL + b*264 + 8*k));
            }
        } else {
            const int off = (s==6)?256:0;
            {
                const int b = tid >> 6, jg = (tid & 63)*4;
                union { u64 q; u16 h[4]; } v; v.q = *(const u64*)(hbL + b*264 + jg);
                float4 o; o.x=bf2f(v.h[0]); o.y=bf2f(v.h[1]); o.z=bf2f(v.h[2]); o.w=bf2f(v.h[3]);
                *(float4*)(out + (size_t)(SEQ-1)*5120 + (size_t)b*512 + off + jg) = o;
            }
            if (wu < 2) {
                const int idx = tid + 512;
                const int b = idx >> 6, jg = (idx & 63)*4;
                union { u64 q; u16 h[4]; } v; v.q = *(const u64*)(hbL + b*264 + jg);
                float4 o; o.x=bf2f(v.h[0]); o.y=bf2f(v.h[1]); o.z=bf2f(v.h[2]); o.w=bf2f(v.h[3]);
                *(float4*)(out + (size_t)(SEQ-1)*5120 + (size_t)b*512 + off + jg) = o;
            }
        }
        wait_vm0(); lgkm_barrier();
        if (tid==0 && s<=4) {
            AST(htp + 508, 509u); AST(htp + 509, 510u);
            AST(htp + 510, 511u); AST(htp + 511, 512u);
        }
        return;
    }

    // ================= HELPERS: gates_x producers (3 WGs/stream) =================
    int sh, t0;
    if (blk < 10)      { sh = 0;               t0 = blk - 7;      }
    else if (blk < 25) { sh = 1 + (blk-10)/3;  t0 = (blk-10)%3;   }
    else               { sh = 6;               t0 = blk - 25;     }

    const int layer = (sh==6)?5:sh, dir=(sh==6)?1:0;
    const float* wihp; int stride;
    if (layer==0){ wihp = wihl0 + (size_t)dir*768*128; stride=128; }
    else         { wihp = wihrest + ((size_t)((layer-1)*2+dir))*768*512; stride=512; }

    // 8 waves x 6 tiles: gate col = (w*6+i)*16 + n16
    short8 bxf[6][4];
#pragma unroll
    for (int i=0; i<6; ++i) {
        const int col = (w*6+i)*16 + n16;
#pragma unroll
        for (int q=0; q<4; ++q)
            bxf[i][q] = ld8f(wihp + (size_t)col*stride + q*32 + quad*8);
    }
    char* tb = (char*)smem_;               // 32 KB slot image
    const int bmA = (n16>9)?9:n16;
    const int lsrc = (sh==6)? 4 : (sh-1);
    u32* gtp_sh = tags + sh*32;

    // Software-pipelined publish: slot t's 16B sc1 stores issued at iter t;
    // tag published at iter t+3 after wait_vm0 + barrier.
    int tprev = -1;
    for (int t = t0; t < SEQ; t += 3) {
        if (t >= 32) {   // ring-32 flow control vs consumer scan (lead <= 24)
            int gd=0;
            while ((int)ALD(cparr + sh) < t-24){ if(++gd>1000000) break; __builtin_amdgcn_s_sleep(8); }
        }
        if (tprev >= 0) {
            wait_vm0();            // own wave's slot-(tprev) stores acked
            __syncthreads();       // all waves acked (+ all tb readers done)
            if (tid==0) AST(gtp_sh + (tprev&31), (u32)(tprev+1));
        }
        short8 ax[4];
        if (sh == 0) {
            const float* xr = x + (size_t)t*1280 + (size_t)bmA*128;
#pragma unroll
            for (int q=0; q<4; ++q) ax[q] = ld8f(xr + q*32 + quad*8);
        } else {
            const int srct = (sh==6)? (SEQ-1-t) : t;
            int gd=0;
            while (ALD(tags + 256 + lsrc*512 + srct) != (u32)(srct+1)){ if(++gd>3000000) break; __builtin_amdgcn_s_sleep(4); }
            const u64* hq = (const u64*)(hhb + (size_t)lsrc*1048576 + (size_t)srct*2048);
#pragma unroll
            for (int q=0; q<4; ++q) {
                u64 a = ALD(hq + n16*32 + q*8 + quad*2);
                u64 b = ALD(hq + n16*32 + q*8 + quad*2 + 1);
                ax[q] = pk2(a, b);
            }
        }
        floatx4 acc[6];
#pragma unroll
        for (int i=0; i<6; ++i) acc[i] = (floatx4){0.f,0.f,0.f,0.f};
#pragma unroll
        for (int q=0; q<4; ++q)
#pragma unroll
            for (int i=0; i<6; ++i)
                acc[i] = __builtin_amdgcn_mfma_f32_16x16x32_bf16(ax[q], bxf[i][q], acc[i], 0,0,0);

        // slot image in LDS: rz bf16 [col<512][16], nx f32 [col-512][16]
        // (tb overwrite is safe: the tag barrier above drained all readers)
#pragma unroll
        for (int i=0; i<6; ++i) {
            const int col = (w*6+i)*16 + n16;
            if (col < 512) *(u64*)(tb + col*32 + quad*8) = pack4bf(acc[i]);
            else           *(floatx4*)(tb + 16384 + (col-512)*64 + quad*16) = acc[i];
        }
        __syncthreads();
        // publish 32KB slot: 4x 16B sc1 stores per thread
        char* gq = (char*)(gring + (size_t)(sh*32 + (t&31))*GSLOT_U64);
#pragma unroll
        for (int k=0;k<4;++k)
            st16_sc1(gq + tid*64 + k*16, *(const floatx4*)((const char*)tb + tid*64 + k*16));
        tprev = t;
    }
    wait_vm0(); __syncthreads();
    if (tid==0 && tprev>=0) AST(gtp_sh + (tprev&31), (u32)(tprev+1));
}

extern "C" void kernel_launch(void* const* d_in, const int* in_sizes, int n_in,
                              void* d_out, int out_size, void* d_ws, size_t ws_size,
                              hipStream_t stream) {
    (void)in_sizes; (void)n_in; (void)out_size; (void)ws_size;
    const float* x       = (const float*)d_in[0];
    const float* wihl0   = (const float*)d_in[1];
    const float* wihrest = (const float*)d_in[2];
    const float* whh     = (const float*)d_in[3];
    float* out = (float*)d_out;
    u64* gring = (u64*)d_ws;
    u16* hhb   = (u16*)((char*)d_ws + (size_t)GRING_U64*8);
    u32* tags  = (u32*)((char*)d_ws + TAGS_OFF_B);

    // No memset: 0xAAAAAAAA poison never equals a valid tag (1..512);
    // flow-control reads cast to int (poison negative => "not yet");
    // LDS tag mirrors hold stale-generation values => slow path, no deadlock.
    gru_pipeline<<<dim3(28), dim3(512), 0, stream>>>(x, wihl0, wihrest, whh, out,
                                                     gring, hhb, tags);
}